// Round 1
// baseline (661.648 us; speedup 1.0000x reference)
//
#include <hip/hip_runtime.h>

// LIF constants folded:
//   i' = s*(1 - DT*TAU_SYN_INV) + x = 0.8*s + x
//   v' = m + DT*TAU_MEM_INV*((0 - m) + i') = 0.9*m + 0.1*i'
//   spike = v' >= 1.0
// Then 2x2 max-pool of the {0,1} spike map.

constexpr int B = 16, C = 64, H = 256, W = 256;
constexpr int OW = W / 2;                       // 128
constexpr int NROWS = B * C * H;                // input rows (flattened over b,c,h)
constexpr int NTHREADS = (NROWS / 2) * (OW / 2); // 1 thread = 2 output px = 2x4 input block

__global__ __launch_bounds__(256) void lif_pool_kernel(
    const float4* __restrict__ x,
    const float4* __restrict__ m,
    const float4* __restrict__ s,
    float2* __restrict__ out)
{
    int t = blockIdx.x * blockDim.x + threadIdx.x;
    if (t >= NTHREADS) return;

    int orow = t >> 6;   // output row index (64 float4-wide thread slots per row)
    int ocp  = t & 63;   // which float4 within the row

    // input float4 index: row 2*orow and 2*orow+1, col group ocp (64 float4 per row)
    int i0 = (2 * orow) * (W / 4) + ocp;
    int i1 = i0 + (W / 4);

    float4 x0 = x[i0], x1 = x[i1];
    float4 m0 = m[i0], m1 = m[i1];
    float4 s0 = s[i0], s1 = s[i1];

    // v = 0.9*m + 0.1*(0.8*s + x)
    float v00 = fmaf(0.9f, m0.x, 0.1f * fmaf(0.8f, s0.x, x0.x));
    float v01 = fmaf(0.9f, m0.y, 0.1f * fmaf(0.8f, s0.y, x0.y));
    float v02 = fmaf(0.9f, m0.z, 0.1f * fmaf(0.8f, s0.z, x0.z));
    float v03 = fmaf(0.9f, m0.w, 0.1f * fmaf(0.8f, s0.w, x0.w));
    float v10 = fmaf(0.9f, m1.x, 0.1f * fmaf(0.8f, s1.x, x1.x));
    float v11 = fmaf(0.9f, m1.y, 0.1f * fmaf(0.8f, s1.y, x1.y));
    float v12 = fmaf(0.9f, m1.z, 0.1f * fmaf(0.8f, s1.z, x1.z));
    float v13 = fmaf(0.9f, m1.w, 0.1f * fmaf(0.8f, s1.w, x1.w));

    // pooled spike = (max of 4 v's in the 2x2 window) >= 1.0 ? 1 : 0
    float w0 = fmaxf(fmaxf(v00, v01), fmaxf(v10, v11));
    float w1 = fmaxf(fmaxf(v02, v03), fmaxf(v12, v13));

    float2 o;
    o.x = (w0 >= 1.0f) ? 1.0f : 0.0f;
    o.y = (w1 >= 1.0f) ? 1.0f : 0.0f;

    out[orow * (OW / 2) + ocp] = o;  // out row has 128 floats = 64 float2
}

extern "C" void kernel_launch(void* const* d_in, const int* in_sizes, int n_in,
                              void* d_out, int out_size, void* d_ws, size_t ws_size,
                              hipStream_t stream) {
    const float4* x = (const float4*)d_in[0];  // input_signal
    const float4* m = (const float4*)d_in[1];  // membrane
    const float4* s = (const float4*)d_in[2];  // synaptic
    float2* out = (float2*)d_out;

    constexpr int BLOCK = 256;
    constexpr int GRID = (NTHREADS + BLOCK - 1) / BLOCK;  // 32768
    lif_pool_kernel<<<GRID, BLOCK, 0, stream>>>(x, m, s, out);
}